// Round 12
// baseline (372.973 us; speedup 1.0000x reference)
//
#include <hip/hip_runtime.h>
#include <stdint.h>

#define B_   4
#define T_   2048
#define D_   768
#define H_   12
#define DH_  64
#define DFF_ 3072
#define NTOK_ (B_*T_)      // 8192
#define QKVN_ (3*D_)       // 2304

typedef unsigned short u16;
typedef unsigned int u32;
typedef __bf16 bf16x8 __attribute__((ext_vector_type(8)));
typedef float  f32x4  __attribute__((ext_vector_type(4)));

__device__ __forceinline__ u16 f2bf(float f) {
  union { float f; unsigned u; } v; v.f = f;
  return (u16)((v.u + 0x7fffu + ((v.u >> 16) & 1u)) >> 16);  // RNE
}

__device__ __forceinline__ float fast_exp2(float x) {
#if __has_builtin(__builtin_amdgcn_exp2f)
  return __builtin_amdgcn_exp2f(x);
#else
  return exp2f(x);
#endif
}

__device__ __forceinline__ float fast_rcp(float x) {
#if __has_builtin(__builtin_amdgcn_rcpf)
  return __builtin_amdgcn_rcpf(x);
#else
  return 1.0f / x;
#endif
}

__device__ __forceinline__ void gload_lds16(const void* g, void* l) {
  __builtin_amdgcn_global_load_lds(
      (__attribute__((address_space(1))) unsigned int*)(void*)g,
      (__attribute__((address_space(3))) unsigned int*)l, 16, 0, 0);
}

// ---------------------------------------------------------------------------
// GEMM: C[m,n] = sum_k A[m,k]*B[n,k]  (A,B bf16; acc fp32)
// 128xBN tiles, 256 thr (4 waves 2x2), BK=64 K-loop — R7 1-phase structure
// (R8/R9 showed source-level prefetch is redundant with TLP here).
//
// R19/R20: BN=256 SUPPORT -> MLP1 gets a 128x256 tile (wave-tile 64x128,
// NI=8). R10 counters (MfmaUtil 25, VALU 37, HBM 18, conflicts 0, nothing
// saturated) left the per-wave MFMA:LDS ratio as the structural cost:
// 64x64 wave-tile = 8 b128 (~96cyc) per 16 MFMA (~80cyc) — LDS pipe
// heavier than matrix pipe. 64x128 wave-tile: 12 b128 (~144) per 32 MFMA
// (~160) — matrix pipe finally dominates; staging/addressing VALU
// amortizes over 2x FLOPs (m93->m97 ladder: tile size was 1.5x).
// LDS 48KB -> 3 blocks/CU; MLP1 grid (64,12)=768 = exactly 3/CU.
// Staging generalized to NBG=BN/64 gload pointers (bit-identical for
// BN=64/128). (R20 = identical resubmit; R19 bench was an infra failure.)
//
// R15 swizzle kept: logical k-chunk j of row r lives at slot j^((r>>1)&3)
// (source-side pre-swizzle; linear LDS dest for global_load_lds); reads
// use chunk quad^((l15>>1)&3) — row-invariant, conflict-free lane-octet
// residues {0,4,1,5,2,6,3,7}, bit-identical numerics. Conflicts = 0.
//
// VTRANS (R12): V columns stored SIGMA-PERMUTED within each 32-t block:
//   pos q*8+j holds s = (j>>2)*16 + q*4 + (j&3) — matches register-direct
//   P in the attention kernel. One contiguous ushort4 store per lane.
// ---------------------------------------------------------------------------
template<bool BIAS, bool RELU, bool RES, bool BF16OUT, bool QSCALE, int BN,
         bool VTRANS>
__global__ __launch_bounds__(256) void gemm_bt(
    const u16* __restrict__ A, const u16* __restrict__ Bw,
    const float* __restrict__ bias, const float* __restrict__ res,
    void* __restrict__ outp, u16* __restrict__ vtp, int M, int N, int K)
{
  constexpr int NI  = BN / 32;           // B-fragments per wave (2/4/8)
  constexpr int NBG = BN / 64;           // B gload ops per BK=32 subtile
  __shared__ u16 lA[2 * 128 * 32];       // two BK=32 sub-tiles
  __shared__ u16 lB[2 * BN * 32];
  const int tid  = threadIdx.x;
  const int lane = tid & 63;
  const int wave = tid >> 6;
  const int quad = lane >> 4;
  const int l15  = lane & 15;
  const int mBase = blockIdx.x * 128;
  const int nBase = blockIdx.y * BN;
  const int wm = (wave >> 1) * 64;
  const int wn = (wave & 1) * (BN / 2);

  const f32x4 fz = {0.f, 0.f, 0.f, 0.f};
  f32x4 acc[4][NI];
#pragma unroll
  for (int i = 0; i < 4; i++)
#pragma unroll
    for (int j = 0; j < NI; j++) acc[i][j] = fz;

  // staging: slot c (16B) -> LDS byte c*16; row = c>>2, holds logical
  // k-chunk j = (c&3) ^ ((row>>1)&3)  (R15 swizzle, source-side)
  const u16* gA[2];
  int cA[2];
#pragma unroll
  for (int i = 0; i < 2; i++) {
    cA[i] = tid + i * 256;
    const int row = cA[i] >> 2, j = (cA[i] & 3) ^ ((row >> 1) & 3);
    gA[i] = A + (size_t)(mBase + row) * K + j * 8;
  }
  const u16* gB[NBG];
  int cB[NBG];
#pragma unroll
  for (int g = 0; g < NBG; g++) {
    cB[g] = tid + g * 256;
    const int row = cB[g] >> 2, j = (cB[g] & 3) ^ ((row >> 1) & 3);
    gB[g] = Bw + (size_t)(nBase + row) * K + j * 8;
  }

  // read-side swizzled chunk (row-invariant): chunk = quad ^ ((l15>>1)&3)
  const int ca = (quad ^ ((l15 >> 1) & 3)) * 8;

  for (int kt = 0; kt < K; kt += 64) {
#pragma unroll
    for (int i = 0; i < 2; i++) {
      gload_lds16(gA[i] + kt,      lA + cA[i] * 8);
      gload_lds16(gA[i] + kt + 32, lA + 128 * 32 + cA[i] * 8);
    }
#pragma unroll
    for (int g = 0; g < NBG; g++) {
      gload_lds16(gB[g] + kt,      lB + cB[g] * 8);
      gload_lds16(gB[g] + kt + 32, lB + BN * 32 + cB[g] * 8);
    }
    __syncthreads();   // drains vmcnt(0) before barrier
#pragma unroll
    for (int hf = 0; hf < 2; hf++) {
      const u16* lAh = lA + hf * (128 * 32);
      const u16* lBh = lB + hf * (BN * 32);
      bf16x8 af[4], bfr[NI];
#pragma unroll
      for (int mi = 0; mi < 4; mi++)
        af[mi] = *(const bf16x8*)(lAh + (wm + mi * 16 + l15) * 32 + ca);
#pragma unroll
      for (int ni = 0; ni < NI; ni++)
        bfr[ni] = *(const bf16x8*)(lBh + (wn + ni * 16 + l15) * 32 + ca);
#pragma unroll
      for (int mi = 0; mi < 4; mi++)
#pragma unroll
        for (int ni = 0; ni < NI; ni++)
          acc[mi][ni] = __builtin_amdgcn_mfma_f32_16x16x32_bf16(
              af[mi], bfr[ni], acc[mi][ni], 0, 0, 0);
    }
    __syncthreads();
  }

#pragma unroll
  for (int mi = 0; mi < 4; mi++) {
#pragma unroll
    for (int ni = 0; ni < NI; ni++) {
      const int col = nBase + wn + ni * 16 + l15;
      if (VTRANS && col >= 2 * D_) {
        // V section -> vt[b,h,d,t'] with sigma-permuted low-5 t bits
        const int n  = col - 2 * D_;
        const int hh = n >> 6, dd = n & 63;
        const int row0 = mBase + wm + mi * 16 + quad * 4;
        const int bb = row0 >> 11, tt = row0 & (T_ - 1);
        const int tperm = (tt & ~31) + 8 * quad + 4 * (mi & 1);
        ushort4 pk;
        pk.x = f2bf(acc[mi][ni][0]); pk.y = f2bf(acc[mi][ni][1]);
        pk.z = f2bf(acc[mi][ni][2]); pk.w = f2bf(acc[mi][ni][3]);
        *(ushort4*)(vtp + ((size_t)((bb * H_ + hh) * DH_ + dd)) * T_ + tperm) = pk;
        continue;
      }
      float bv = 0.f;
      if (BIAS) bv = bias[col];
#pragma unroll
      for (int r = 0; r < 4; r++) {
        const int row = mBase + wm + mi * 16 + quad * 4 + r;  // C/D: row=quad*4+r, col=lane&15
        float v = acc[mi][ni][r];
        if (BIAS) v += bv;
        if (RELU) v = fmaxf(v, 0.f);
        if (RES)  v += res[(size_t)row * N + col];
        if (QSCALE && col < D_) v *= 0.180336880f;   // 0.125 * log2(e)
        if (BF16OUT) ((u16*)outp)[(size_t)row * N + col] = f2bf(v);
        else        ((float*)outp)[(size_t)row * N + col] = v;
      }
    }
  }
}

// ---------------------------------------------------------------------------
// Flash attention, causal — S^T dataflow, register-direct P (unchanged).
// XCD-chunked block remap (R18): nid = (lid&7)*96 + (lid>>3) — each XCD
// owns 6 complete (b,h) K/V groups (3MB < 4MB L2).
// Sequential complementary tiles (heavy 31-pi then light pi), 4 waves x 16
// q-rows, 33 uniform rounds/block, 3 blocks/CU, K/V double-buffered,
// sigma-permuted vt so PV A-frags reuse K's b128 offsets; thin VALU softmax.
// ---------------------------------------------------------------------------
__device__ __forceinline__ void attn_round(
    const u16* __restrict__ lKc, const u16* __restrict__ lVc,
    int s0, int qw0, int quad, int l15,
    int kc0, int kc1,
    const bf16x8& q0, const bf16x8& q1,
    f32x4 (&o)[4], float& ls)
{
  const f32x4 fz = {0.f, 0.f, 0.f, 0.f};
  // S^T = K Q^T: rows s (m=l15 per 16-tile), cols q (n=l15 of B)
  f32x4 s[4];
#pragma unroll
  for (int ni = 0; ni < 4; ni++) {
    const int rb = (ni * 16 + l15) * 64;
    const bf16x8 k0 = *(const bf16x8*)(lKc + rb + kc0);
    const bf16x8 k1 = *(const bf16x8*)(lKc + rb + kc1);
    f32x4 t = fz;
    t = __builtin_amdgcn_mfma_f32_16x16x32_bf16(k0, q0, t, 0, 0, 0);
    t = __builtin_amdgcn_mfma_f32_16x16x32_bf16(k1, q1, t, 0, 0, 0);
    s[ni] = t;
  }

  // p = exp2(s'); mask s>q only on the straddling (diagonal) tile.
  // nm is wave-uniform -> scalar branch; clean path for 31 of 33 rounds.
  const bool nm = (s0 + 63 > qw0);
  union { __bf16 h[16]; bf16x8 v[2]; } P;
  float ls0 = 0.f, ls1 = 0.f;
  if (nm) {
    const int qidx = qw0 + l15;
#pragma unroll
    for (int ni = 0; ni < 4; ni++) {
      const int sbase = s0 + ni * 16 + quad * 4;
#pragma unroll
      for (int r = 0; r < 4; r++) {
        float v = fast_exp2(s[ni][r]);
        if (sbase + r > qidx) v = 0.f;
        P.h[ni * 4 + r] = (__bf16)v;
        if (r & 1) ls1 += v; else ls0 += v;
      }
    }
  } else {
#pragma unroll
    for (int ni = 0; ni < 4; ni++) {
#pragma unroll
      for (int r = 0; r < 4; r++) {
        float v = fast_exp2(s[ni][r]);
        P.h[ni * 4 + r] = (__bf16)v;
        if (r & 1) ls1 += v; else ls0 += v;
      }
    }
  }
  ls += ls0 + ls1;

  // O^T += V^T P^T: V stored sigma-permuted, so canonical b128 A-frags
  // (same offsets as K) line up with P's register order.
#pragma unroll
  for (int dt = 0; dt < 4; dt++) {
    const int rb = (dt * 16 + l15) * 64;
    const bf16x8 v0 = *(const bf16x8*)(lVc + rb + kc0);
    const bf16x8 v1 = *(const bf16x8*)(lVc + rb + kc1);
    o[dt] = __builtin_amdgcn_mfma_f32_16x16x32_bf16(v0, P.v[0], o[dt], 0, 0, 0);
    o[dt] = __builtin_amdgcn_mfma_f32_16x16x32_bf16(v1, P.v[1], o[dt], 0, 0, 0);
  }
}

__global__ __launch_bounds__(256) void attn_kernel(
    const u16* __restrict__ qkv, const u16* __restrict__ vt, u16* __restrict__ Y)
{
  __shared__ u16 lK[2][64 * 64];
  __shared__ u16 lV[2][64 * 64];
  const int tid  = threadIdx.x;
  const int lane = tid & 63;
  const int wave = tid >> 6;
  const int quad = lane >> 4;
  const int l15  = lane & 15;
  // XCD-chunked remap: linear id -> nid so each XCD (id%8 under round-robin
  // dispatch) owns 96 consecutive nids = 6 complete (b,h) K/V groups.
  const int lid = (int)(blockIdx.x + 16 * blockIdx.y + 192 * blockIdx.z);
  const int nid = (lid & 7) * 96 + (lid >> 3);
  const int pi = nid & 15;             // 0..15
  const int h  = (nid >> 4) % 12;
  const int b  = nid / 192;
  const int tH = 31 - pi, tL = pi;     // heavy first, then light (re-stage s=0)
  const int njsH = tH + 1;             // 32-pi rounds
  const int total = njsH + tL + 1;     // 33 rounds, uniform for every block
  const int qwH = tH * 64 + wave * 16; // wave's 16 q-rows in each tile
  const int qwL = tL * 64 + wave * 16;

  // swizzled LDS column offsets (sw = l15&7 is row-invariant: rows stride 16)
  const int sw  = l15 & 7;
  const int kc0 = (quad ^ sw) * 8;
  const int kc1 = ((4 + quad) ^ sw) * 8;

  // Q B-frags for both tiles (pre-scaled by 0.125*log2e)
  bf16x8 qH0, qH1, qL0, qL1;
  {
    const u16* qp = qkv + (size_t)(b * T_ + qwH + l15) * QKVN_ + h * DH_ + quad * 8;
    qH0 = *(const bf16x8*)(qp);
    qH1 = *(const bf16x8*)(qp + 32);
    const u16* qp2 = qkv + (size_t)(b * T_ + qwL + l15) * QKVN_ + h * DH_ + quad * 8;
    qL0 = *(const bf16x8*)(qp2);
    qL1 = *(const bf16x8*)(qp2 + 32);
  }

  const f32x4 fz = {0.f, 0.f, 0.f, 0.f};
  f32x4 oH[4], oL[4];
#pragma unroll
  for (int i = 0; i < 4; i++) { oH[i] = fz; oL[i] = fz; }
  float lsH = 0.f, lsL = 0.f;

  // swizzled staging: LDS chunk c holds logical chunk j = (c&7)^(row&7)
  const int c0 = tid, c1 = tid + 256;
  const int r0 = c0 >> 3, j0 = (c0 & 7) ^ (r0 & 7);
  const int r1 = c1 >> 3, j1 = (c1 & 7) ^ (r1 & 7);
  const u16* gK0 = qkv + (size_t)(b * T_ + r0) * QKVN_ + D_ + h * DH_ + j0 * 8;
  const u16* gK1 = qkv + (size_t)(b * T_ + r1) * QKVN_ + D_ + h * DH_ + j1 * 8;
  const u16* gV0 = vt + (size_t)((b * H_ + h) * DH_ + r0) * T_ + j0 * 8;
  const u16* gV1 = vt + (size_t)((b * H_ + h) * DH_ + r1) * T_ + j1 * 8;

  // preload s-tile 0 into buffer 0
  gload_lds16(gK0, lK[0] + c0 * 8);
  gload_lds16(gK1, lK[0] + c1 * 8);
  gload_lds16(gV0, lV[0] + c0 * 8);
  gload_lds16(gV1, lV[0] + c1 * 8);

  for (int i = 0; i < total; i++) {
    const int cur = i & 1;
    __syncthreads();   // drains vmcnt(0): buf[cur] staged; prev readers done

    if (i + 1 < total) {   // prefetch next s-tile (wraps to 0 at phase switch)
      const int sn = (i + 1 < njsH) ? (i + 1) : (i + 1 - njsH);
      const size_t s1 = (size_t)sn * 64;
      const int nb = cur ^ 1;
      gload_lds16(gK0 + s1 * QKVN_, lK[nb] + c0 * 8);
      gload_lds16(gK1 + s1 * QKVN_, lK[nb] + c1 * 8);
      gload_lds16(gV0 + s1,         lV[nb] + c0 * 8);
      gload_lds16(gV1 + s1,         lV[nb] + c1 * 8);
    }

    const u16* lKc = lK[cur];
    const u16* lVc = lV[cur];
    if (i < njsH) {
      attn_round(lKc, lVc, i * 64, qwH, quad, l15, kc0, kc1,
                 qH0, qH1, oH, lsH);
    } else {
      attn_round(lKc, lVc, (i - njsH) * 64, qwL, quad, l15, kc0, kc1,
                 qL0, qL1, oL, lsL);
    }
  }

  // l reduction: sum across the 4 quads (same l15 = same q column)
  lsH += __shfl_xor(lsH, 16); lsH += __shfl_xor(lsH, 32);
  lsL += __shfl_xor(lsL, 16); lsL += __shfl_xor(lsL, 32);
  const float rlH = fast_rcp(lsH);
  const float rlL = fast_rcp(lsL);

  // O^T: col q = l15, row d = dt*16 + quad*4 + r -> packed ushort4 per dt
#pragma unroll
  for (int dt = 0; dt < 4; dt++) {
    const int dbase = h * DH_ + dt * 16 + quad * 4;
    ushort4 pa, pb;
    pa.x = f2bf(oH[dt][0] * rlH); pa.y = f2bf(oH[dt][1] * rlH);
    pa.z = f2bf(oH[dt][2] * rlH); pa.w = f2bf(oH[dt][3] * rlH);
    pb.x = f2bf(oL[dt][0] * rlL); pb.y = f2bf(oL[dt][1] * rlL);
    pb.z = f2bf(oL[dt][2] * rlL); pb.w = f2bf(oL[dt][3] * rlL);
    *(ushort4*)(Y + (size_t)(b * T_ + qwH + l15) * D_ + dbase) = pa;
    *(ushort4*)(Y + (size_t)(b * T_ + qwL + l15) * D_ + dbase) = pb;
  }
}

// ---------------------------------------------------------------------------
// LayerNorm over D=768, fp32 in -> bf16 out. 1 block / row.
// ---------------------------------------------------------------------------
__device__ __forceinline__ void ln_row(
    const float* __restrict__ X, const float* __restrict__ g,
    const float* __restrict__ be, u16* __restrict__ out, int row)
{
  const float* x = X + (size_t)row * D_;
  const int t = threadIdx.x;
  const float v0 = x[t], v1 = x[t + 256], v2 = x[t + 512];
  float s = v0 + v1 + v2;
  float sq = v0 * v0 + v1 * v1 + v2 * v2;
#pragma unroll
  for (int off = 1; off < 64; off <<= 1) {
    s  += __shfl_xor(s, off);
    sq += __shfl_xor(sq, off);
  }
  __shared__ float ws_[4], wq_[4];
  const int wv = t >> 6, lane = t & 63;
  if (lane == 0) { ws_[wv] = s; wq_[wv] = sq; }
  __syncthreads();
  s  = ws_[0] + ws_[1] + ws_[2] + ws_[3];
  sq = wq_[0] + wq_[1] + wq_[2] + wq_[3];
  const float mean = s * (1.f / 768.f);
  const float var  = sq * (1.f / 768.f) - mean * mean;
  const float rstd = rsqrtf(var + 1e-5f);
  u16* o = out + (size_t)row * D_;
  int c = t;
  o[c] = f2bf((v0 - mean) * rstd * g[c] + be[c]); c += 256;
  o[c] = f2bf((v1 - mean) * rstd * g[c] + be[c]); c += 256;
  o[c] = f2bf((v2 - mean) * rstd * g[c] + be[c]);
}

__global__ __launch_bounds__(256) void ln_kernel(
    const float* __restrict__ X, const float* __restrict__ g,
    const float* __restrict__ be, u16* __restrict__ out)
{
  ln_row(X, g, be, out, blockIdx.x);
}

// ---------------------------------------------------------------------------
// Prep kernel: LN1 (blocks [0,8192)) + all weight converts (one launch):
//   blocks [8192, 8336)   : w_o 768x768 transpose-convert -> woT
//   blocks [8336, 33680)  : flat fp32->bf16 of w_q|w_k|w_v -> wqkv, W1, W2
// ---------------------------------------------------------------------------
__global__ __launch_bounds__(256) void prep_kernel(
    const float* __restrict__ X, const float* __restrict__ g1,
    const float* __restrict__ be1, u16* __restrict__ xln,
    const float* __restrict__ w_q, const float* __restrict__ w_k,
    const float* __restrict__ w_v, const float* __restrict__ W1,
    const float* __restrict__ W2, const float* __restrict__ w_o,
    u16* __restrict__ wqkv, u16* __restrict__ W1b,
    u16* __restrict__ W2b, u16* __restrict__ woT)
{
  if (blockIdx.x < NTOK_) {
    ln_row(X, g1, be1, xln, blockIdx.x);
    return;
  }
  const int id = blockIdx.x - NTOK_;
  if (id < 144) {
    __shared__ float tile[64][65];
    const int bx = id % 12, by = id / 12;
    const int rr0 = by * 64, cc0 = bx * 64;
    for (int idx = threadIdx.x; idx < 4096; idx += 256) {
      const int i = idx >> 6, j = idx & 63;
      tile[i][j] = w_o[(size_t)(rr0 + i) * D_ + cc0 + j];
    }
    __syncthreads();
    for (int idx = threadIdx.x; idx < 4096; idx += 256) {
      const int i = idx >> 6, j = idx & 63;
      woT[(size_t)(cc0 + i) * D_ + rr0 + j] = f2bf(tile[j][i]);
    }
  } else {
    const int WQN = H_ * DH_ * D_;            // 589824
    const int i = (id - 144) * 256 + threadIdx.x;
    if (i < 3 * WQN) {
      const float* src = (i < WQN) ? w_q : (i < 2 * WQN ? w_k : w_v);
      const int off = (i < WQN) ? i : (i < 2 * WQN ? i - WQN : i - 2 * WQN);
      wqkv[i] = f2bf(src[off]);
    } else if (i < 3 * WQN + DFF_ * D_) {
      const int off = i - 3 * WQN;
      W1b[off] = f2bf(W1[off]);
    } else {
      const int off = i - 3 * WQN - DFF_ * D_;
      W2b[off] = f2bf(W2[off]);
    }
  }
}

// ---------------------------------------------------------------------------
extern "C" void kernel_launch(void* const* d_in, const int* in_sizes, int n_in,
                              void* d_out, int out_size, void* d_ws, size_t ws_size,
                              hipStream_t stream) {
  const float* X   = (const float*)d_in[0];
  const float* w_q = (const float*)d_in[1];
  const float* w_k = (const float*)d_in[2];
  const float* w_v = (const float*)d_in[3];
  const float* w_o = (const float*)d_in[4];
  const float* W1  = (const float*)d_in[5];
  const float* b1  = (const float*)d_in[6];
  const float* W2  = (const float*)d_in[7];
  const float* b2  = (const float*)d_in[8];
  const float* g1  = (const float*)d_in[9];
  const float* be1 = (const float*)d_in[10];
  const float* g2  = (const float*)d_in[11];
  const float* be2 = (const float*)d_in[12];
  float* out = (float*)d_out;

  char* ws = (char*)d_ws;
  // region A: qkv(37.7M)+vt(12.6M) -> later aliased by h(50.3M)
  u16*   qkv  = (u16*)(ws + 0);
  u16*   vt   = (u16*)(ws + 37748736);
  u16*   hbuf = (u16*)(ws + 0);
  u16*   xln  = (u16*)(ws + 50331648);   // aliased: xln then x2ln
  u16*   Ybuf = (u16*)(ws + 62914560);
  float* X1   = (float*)(ws + 75497472);
  u16*   wqkv = (u16*)(ws + 100663296);
  u16*   woT  = (u16*)(ws + 104202240);
  u16*   W1b  = (u16*)(ws + 105381888);
  u16*   W2b  = (u16*)(ws + 110100480);  // end 114819072

  // LN1 + all weight converts in one launch
  prep_kernel<<<NTOK_ + 25488, 256, 0, stream>>>(
      X, g1, be1, xln, w_q, w_k, w_v, W1, W2, w_o, wqkv, W1b, W2b, woT);

  // QKV: [8192,768] x [2304,768]^T; Q cols pre-scaled; V routed to vt transposed
  gemm_bt<false, false, false, true, true, 128, true>
      <<<dim3(64, 18), 256, 0, stream>>>(
      xln, wqkv, nullptr, nullptr, qkv, vt, NTOK_, QKVN_, D_);

  attn_kernel<<<dim3(16, 12, 4), 256, 0, stream>>>(qkv, vt, Ybuf);

  // O-proj + residual X -> X1 (fp32); BN=64 -> 768 blocks (3/CU)
  gemm_bt<false, false, true, false, false, 64, false>
      <<<dim3(64, 12), 256, 0, stream>>>(
      Ybuf, woT, nullptr, X, X1, nullptr, NTOK_, D_, D_);

  ln_kernel<<<NTOK_, 256, 0, stream>>>(X1, g2, be2, xln);

  // MLP1: +b1, ReLU -> bf16 h; 128x256 tile -> (64,12)=768 blocks = 3/CU
  gemm_bt<true, true, false, true, false, 256, false>
      <<<dim3(64, 12), 256, 0, stream>>>(
      xln, W1b, b1, nullptr, hbuf, nullptr, NTOK_, DFF_, D_);

  // MLP2: +b2, +X1 -> d_out (fp32); BN=64 -> 768 blocks (3/CU)
  gemm_bt<true, false, true, false, false, 64, false>
      <<<dim3(64, 12), 256, 0, stream>>>(
      hbuf, W2b, b2, X1, out, nullptr, NTOK_, D_, DFF_);
}

// Round 13
// 337.378 us; speedup vs baseline: 1.1055x; 1.1055x over previous
//
#include <hip/hip_runtime.h>
#include <stdint.h>

#define B_   4
#define T_   2048
#define D_   768
#define H_   12
#define DH_  64
#define DFF_ 3072
#define NTOK_ (B_*T_)      // 8192
#define QKVN_ (3*D_)       // 2304

typedef unsigned short u16;
typedef unsigned int u32;
typedef __bf16 bf16x8 __attribute__((ext_vector_type(8)));
typedef float  f32x4  __attribute__((ext_vector_type(4)));

__device__ __forceinline__ u16 f2bf(float f) {
  union { float f; unsigned u; } v; v.f = f;
  return (u16)((v.u + 0x7fffu + ((v.u >> 16) & 1u)) >> 16);  // RNE
}

__device__ __forceinline__ float fast_exp2(float x) {
#if __has_builtin(__builtin_amdgcn_exp2f)
  return __builtin_amdgcn_exp2f(x);
#else
  return exp2f(x);
#endif
}

__device__ __forceinline__ float fast_rcp(float x) {
#if __has_builtin(__builtin_amdgcn_rcpf)
  return __builtin_amdgcn_rcpf(x);
#else
  return 1.0f / x;
#endif
}

__device__ __forceinline__ void gload_lds16(const void* g, void* l) {
  __builtin_amdgcn_global_load_lds(
      (__attribute__((address_space(1))) unsigned int*)(void*)g,
      (__attribute__((address_space(3))) unsigned int*)l, 16, 0, 0);
}

// ---------------------------------------------------------------------------
// GEMM: C[m,n] = sum_k A[m,k]*B[n,k]  (A,B bf16; acc fp32)
// 128xBN tiles, 256 thr (4 waves 2x2), BK=64 K-loop.
//
// R21: (a) MLP1 reverted to BN=128 — R12 proved residency is the currency:
// LDS 32->48KB cut blocks/CU 5->3 and every counter scaled by that ratio.
// (b) VPIPE (BN=64 GEMMs: O-proj, MLP2): depth-2 counted-vmcnt pipeline
// (T4) with raw s_barrier — NO __syncthreads -> no vmcnt(0) drain in the
// K-loop. Each wave: s_waitcnt vmcnt(6) waits only its OWN stage(t) loads
// (stage(t+1)'s 6 stay in flight); s_barrier then gives cross-wave tile
// completeness (each wave drained its own contribution); stage(t+2) issues
// after the read-release barrier. MLP2 has 48 drain windows of ~80cyc MFMA
// vs ~300cyc latency — the drain fraction is 3x the regime where m139
// measured this neutral. LDS 24->48KB (residency 6->3): betting drain
// elimination > lost TLP. Numerics bit-identical.
//
// R15 swizzle kept: logical k-chunk j of row r lives at slot j^((r>>1)&3)
// (source-side pre-swizzle; linear LDS dest for global_load_lds); reads
// use chunk quad^((l15>>1)&3) — row-invariant, conflict-free lane-octet
// residues {0,4,1,5,2,6,3,7}, bit-identical numerics. Conflicts = 0.
//
// VTRANS (R12): V columns stored SIGMA-PERMUTED within each 32-t block:
//   pos q*8+j holds s = (j>>2)*16 + q*4 + (j&3) — matches register-direct
//   P in the attention kernel. One contiguous ushort4 store per lane.
// ---------------------------------------------------------------------------
template<bool BIAS, bool RELU, bool RES, bool BF16OUT, bool QSCALE, int BN,
         bool VTRANS, bool VPIPE>
__global__ __launch_bounds__(256) void gemm_bt(
    const u16* __restrict__ A, const u16* __restrict__ Bw,
    const float* __restrict__ bias, const float* __restrict__ res,
    void* __restrict__ outp, u16* __restrict__ vtp, int M, int N, int K)
{
  constexpr int NI   = BN / 32;          // B-fragments per wave
  constexpr int NBG  = BN / 64;          // B gload ops per BK=32 subtile
  constexpr int NBUF = VPIPE ? 2 : 1;
  __shared__ u16 lA[NBUF][2 * 128 * 32]; // per buf: two BK=32 sub-tiles
  __shared__ u16 lB[NBUF][2 * BN * 32];
  const int tid  = threadIdx.x;
  const int lane = tid & 63;
  const int wave = tid >> 6;
  const int quad = lane >> 4;
  const int l15  = lane & 15;
  const int mBase = blockIdx.x * 128;
  const int nBase = blockIdx.y * BN;
  const int wm = (wave >> 1) * 64;
  const int wn = (wave & 1) * (BN / 2);

  const f32x4 fz = {0.f, 0.f, 0.f, 0.f};
  f32x4 acc[4][NI];
#pragma unroll
  for (int i = 0; i < 4; i++)
#pragma unroll
    for (int j = 0; j < NI; j++) acc[i][j] = fz;

  // staging: slot c (16B) -> LDS byte c*16; row = c>>2, holds logical
  // k-chunk j = (c&3) ^ ((row>>1)&3)  (R15 swizzle, source-side)
  const u16* gA[2];
  int cA[2];
#pragma unroll
  for (int i = 0; i < 2; i++) {
    cA[i] = tid + i * 256;
    const int row = cA[i] >> 2, j = (cA[i] & 3) ^ ((row >> 1) & 3);
    gA[i] = A + (size_t)(mBase + row) * K + j * 8;
  }
  const u16* gB[NBG];
  int cB[NBG];
#pragma unroll
  for (int g = 0; g < NBG; g++) {
    cB[g] = tid + g * 256;
    const int row = cB[g] >> 2, j = (cB[g] & 3) ^ ((row >> 1) & 3);
    gB[g] = Bw + (size_t)(nBase + row) * K + j * 8;
  }

  // read-side swizzled chunk (row-invariant): chunk = quad ^ ((l15>>1)&3)
  const int ca = (quad ^ ((l15 >> 1) & 3)) * 8;

  auto stage = [&](int kt, int buf) {
#pragma unroll
    for (int i = 0; i < 2; i++) {
      gload_lds16(gA[i] + kt,      lA[buf] + cA[i] * 8);
      gload_lds16(gA[i] + kt + 32, lA[buf] + 128 * 32 + cA[i] * 8);
    }
#pragma unroll
    for (int g = 0; g < NBG; g++) {
      gload_lds16(gB[g] + kt,      lB[buf] + cB[g] * 8);
      gload_lds16(gB[g] + kt + 32, lB[buf] + BN * 32 + cB[g] * 8);
    }
  };

  auto compute = [&](int buf) {
#pragma unroll
    for (int hf = 0; hf < 2; hf++) {
      const u16* lAh = lA[buf] + hf * (128 * 32);
      const u16* lBh = lB[buf] + hf * (BN * 32);
      bf16x8 af[4], bfr[NI];
#pragma unroll
      for (int mi = 0; mi < 4; mi++)
        af[mi] = *(const bf16x8*)(lAh + (wm + mi * 16 + l15) * 32 + ca);
#pragma unroll
      for (int ni = 0; ni < NI; ni++)
        bfr[ni] = *(const bf16x8*)(lBh + (wn + ni * 16 + l15) * 32 + ca);
#pragma unroll
      for (int mi = 0; mi < 4; mi++)
#pragma unroll
        for (int ni = 0; ni < NI; ni++)
          acc[mi][ni] = __builtin_amdgcn_mfma_f32_16x16x32_bf16(
              af[mi], bfr[ni], acc[mi][ni], 0, 0, 0);
    }
  };

  if constexpr (VPIPE) {
    static_assert(BN == 64, "VPIPE vmcnt count assumes 6 loads/stage");
    const int nk = K >> 6;               // >= 2 for all our shapes
    stage(0, 0);
    stage(64, 1);
    for (int t = 0; t < nk; t++) {
      // wait for OWN stage(t) loads only; stage(t+1)'s 6 stay in flight
      if (t + 1 < nk) asm volatile("s_waitcnt vmcnt(6)" ::: "memory");
      else            asm volatile("s_waitcnt vmcnt(0)" ::: "memory");
      __builtin_amdgcn_s_barrier();      // all waves drained their part
      compute(t & 1);
      __builtin_amdgcn_s_barrier();      // read-release before overwrite
      if (t + 2 < nk) stage((t + 2) * 64, t & 1);
    }
  } else {
    for (int kt = 0; kt < K; kt += 64) {
      stage(kt, 0);
      __syncthreads();   // drains vmcnt(0) before barrier
      compute(0);
      __syncthreads();
    }
  }

#pragma unroll
  for (int mi = 0; mi < 4; mi++) {
#pragma unroll
    for (int ni = 0; ni < NI; ni++) {
      const int col = nBase + wn + ni * 16 + l15;
      if (VTRANS && col >= 2 * D_) {
        // V section -> vt[b,h,d,t'] with sigma-permuted low-5 t bits
        const int n  = col - 2 * D_;
        const int hh = n >> 6, dd = n & 63;
        const int row0 = mBase + wm + mi * 16 + quad * 4;
        const int bb = row0 >> 11, tt = row0 & (T_ - 1);
        const int tperm = (tt & ~31) + 8 * quad + 4 * (mi & 1);
        ushort4 pk;
        pk.x = f2bf(acc[mi][ni][0]); pk.y = f2bf(acc[mi][ni][1]);
        pk.z = f2bf(acc[mi][ni][2]); pk.w = f2bf(acc[mi][ni][3]);
        *(ushort4*)(vtp + ((size_t)((bb * H_ + hh) * DH_ + dd)) * T_ + tperm) = pk;
        continue;
      }
      float bv = 0.f;
      if (BIAS) bv = bias[col];
#pragma unroll
      for (int r = 0; r < 4; r++) {
        const int row = mBase + wm + mi * 16 + quad * 4 + r;  // C/D: row=quad*4+r, col=lane&15
        float v = acc[mi][ni][r];
        if (BIAS) v += bv;
        if (RELU) v = fmaxf(v, 0.f);
        if (RES)  v += res[(size_t)row * N + col];
        if (QSCALE && col < D_) v *= 0.180336880f;   // 0.125 * log2(e)
        if (BF16OUT) ((u16*)outp)[(size_t)row * N + col] = f2bf(v);
        else        ((float*)outp)[(size_t)row * N + col] = v;
      }
    }
  }
}

// ---------------------------------------------------------------------------
// Flash attention, causal — S^T dataflow, register-direct P (unchanged).
// XCD-chunked block remap (R18): nid = (lid&7)*96 + (lid>>3) — each XCD
// owns 6 complete (b,h) K/V groups (3MB < 4MB L2).
// Sequential complementary tiles (heavy 31-pi then light pi), 4 waves x 16
// q-rows, 33 uniform rounds/block, 3 blocks/CU, K/V double-buffered,
// sigma-permuted vt so PV A-frags reuse K's b128 offsets; thin VALU softmax.
// ---------------------------------------------------------------------------
__device__ __forceinline__ void attn_round(
    const u16* __restrict__ lKc, const u16* __restrict__ lVc,
    int s0, int qw0, int quad, int l15,
    int kc0, int kc1,
    const bf16x8& q0, const bf16x8& q1,
    f32x4 (&o)[4], float& ls)
{
  const f32x4 fz = {0.f, 0.f, 0.f, 0.f};
  // S^T = K Q^T: rows s (m=l15 per 16-tile), cols q (n=l15 of B)
  f32x4 s[4];
#pragma unroll
  for (int ni = 0; ni < 4; ni++) {
    const int rb = (ni * 16 + l15) * 64;
    const bf16x8 k0 = *(const bf16x8*)(lKc + rb + kc0);
    const bf16x8 k1 = *(const bf16x8*)(lKc + rb + kc1);
    f32x4 t = fz;
    t = __builtin_amdgcn_mfma_f32_16x16x32_bf16(k0, q0, t, 0, 0, 0);
    t = __builtin_amdgcn_mfma_f32_16x16x32_bf16(k1, q1, t, 0, 0, 0);
    s[ni] = t;
  }

  // p = exp2(s'); mask s>q only on the straddling (diagonal) tile.
  // nm is wave-uniform -> scalar branch; clean path for 31 of 33 rounds.
  const bool nm = (s0 + 63 > qw0);
  union { __bf16 h[16]; bf16x8 v[2]; } P;
  float ls0 = 0.f, ls1 = 0.f;
  if (nm) {
    const int qidx = qw0 + l15;
#pragma unroll
    for (int ni = 0; ni < 4; ni++) {
      const int sbase = s0 + ni * 16 + quad * 4;
#pragma unroll
      for (int r = 0; r < 4; r++) {
        float v = fast_exp2(s[ni][r]);
        if (sbase + r > qidx) v = 0.f;
        P.h[ni * 4 + r] = (__bf16)v;
        if (r & 1) ls1 += v; else ls0 += v;
      }
    }
  } else {
#pragma unroll
    for (int ni = 0; ni < 4; ni++) {
#pragma unroll
      for (int r = 0; r < 4; r++) {
        float v = fast_exp2(s[ni][r]);
        P.h[ni * 4 + r] = (__bf16)v;
        if (r & 1) ls1 += v; else ls0 += v;
      }
    }
  }
  ls += ls0 + ls1;

  // O^T += V^T P^T: V stored sigma-permuted, so canonical b128 A-frags
  // (same offsets as K) line up with P's register order.
#pragma unroll
  for (int dt = 0; dt < 4; dt++) {
    const int rb = (dt * 16 + l15) * 64;
    const bf16x8 v0 = *(const bf16x8*)(lVc + rb + kc0);
    const bf16x8 v1 = *(const bf16x8*)(lVc + rb + kc1);
    o[dt] = __builtin_amdgcn_mfma_f32_16x16x32_bf16(v0, P.v[0], o[dt], 0, 0, 0);
    o[dt] = __builtin_amdgcn_mfma_f32_16x16x32_bf16(v1, P.v[1], o[dt], 0, 0, 0);
  }
}

__global__ __launch_bounds__(256) void attn_kernel(
    const u16* __restrict__ qkv, const u16* __restrict__ vt, u16* __restrict__ Y)
{
  __shared__ u16 lK[2][64 * 64];
  __shared__ u16 lV[2][64 * 64];
  const int tid  = threadIdx.x;
  const int lane = tid & 63;
  const int wave = tid >> 6;
  const int quad = lane >> 4;
  const int l15  = lane & 15;
  // XCD-chunked remap: linear id -> nid so each XCD (id%8 under round-robin
  // dispatch) owns 96 consecutive nids = 6 complete (b,h) K/V groups.
  const int lid = (int)(blockIdx.x + 16 * blockIdx.y + 192 * blockIdx.z);
  const int nid = (lid & 7) * 96 + (lid >> 3);
  const int pi = nid & 15;             // 0..15
  const int h  = (nid >> 4) % 12;
  const int b  = nid / 192;
  const int tH = 31 - pi, tL = pi;     // heavy first, then light (re-stage s=0)
  const int njsH = tH + 1;             // 32-pi rounds
  const int total = njsH + tL + 1;     // 33 rounds, uniform for every block
  const int qwH = tH * 64 + wave * 16; // wave's 16 q-rows in each tile
  const int qwL = tL * 64 + wave * 16;

  // swizzled LDS column offsets (sw = l15&7 is row-invariant: rows stride 16)
  const int sw  = l15 & 7;
  const int kc0 = (quad ^ sw) * 8;
  const int kc1 = ((4 + quad) ^ sw) * 8;

  // Q B-frags for both tiles (pre-scaled by 0.125*log2e)
  bf16x8 qH0, qH1, qL0, qL1;
  {
    const u16* qp = qkv + (size_t)(b * T_ + qwH + l15) * QKVN_ + h * DH_ + quad * 8;
    qH0 = *(const bf16x8*)(qp);
    qH1 = *(const bf16x8*)(qp + 32);
    const u16* qp2 = qkv + (size_t)(b * T_ + qwL + l15) * QKVN_ + h * DH_ + quad * 8;
    qL0 = *(const bf16x8*)(qp2);
    qL1 = *(const bf16x8*)(qp2 + 32);
  }

  const f32x4 fz = {0.f, 0.f, 0.f, 0.f};
  f32x4 oH[4], oL[4];
#pragma unroll
  for (int i = 0; i < 4; i++) { oH[i] = fz; oL[i] = fz; }
  float lsH = 0.f, lsL = 0.f;

  // swizzled staging: LDS chunk c holds logical chunk j = (c&7)^(row&7)
  const int c0 = tid, c1 = tid + 256;
  const int r0 = c0 >> 3, j0 = (c0 & 7) ^ (r0 & 7);
  const int r1 = c1 >> 3, j1 = (c1 & 7) ^ (r1 & 7);
  const u16* gK0 = qkv + (size_t)(b * T_ + r0) * QKVN_ + D_ + h * DH_ + j0 * 8;
  const u16* gK1 = qkv + (size_t)(b * T_ + r1) * QKVN_ + D_ + h * DH_ + j1 * 8;
  const u16* gV0 = vt + (size_t)((b * H_ + h) * DH_ + r0) * T_ + j0 * 8;
  const u16* gV1 = vt + (size_t)((b * H_ + h) * DH_ + r1) * T_ + j1 * 8;

  // preload s-tile 0 into buffer 0
  gload_lds16(gK0, lK[0] + c0 * 8);
  gload_lds16(gK1, lK[0] + c1 * 8);
  gload_lds16(gV0, lV[0] + c0 * 8);
  gload_lds16(gV1, lV[0] + c1 * 8);

  for (int i = 0; i < total; i++) {
    const int cur = i & 1;
    __syncthreads();   // drains vmcnt(0): buf[cur] staged; prev readers done

    if (i + 1 < total) {   // prefetch next s-tile (wraps to 0 at phase switch)
      const int sn = (i + 1 < njsH) ? (i + 1) : (i + 1 - njsH);
      const size_t s1 = (size_t)sn * 64;
      const int nb = cur ^ 1;
      gload_lds16(gK0 + s1 * QKVN_, lK[nb] + c0 * 8);
      gload_lds16(gK1 + s1 * QKVN_, lK[nb] + c1 * 8);
      gload_lds16(gV0 + s1,         lV[nb] + c0 * 8);
      gload_lds16(gV1 + s1,         lV[nb] + c1 * 8);
    }

    const u16* lKc = lK[cur];
    const u16* lVc = lV[cur];
    if (i < njsH) {
      attn_round(lKc, lVc, i * 64, qwH, quad, l15, kc0, kc1,
                 qH0, qH1, oH, lsH);
    } else {
      attn_round(lKc, lVc, (i - njsH) * 64, qwL, quad, l15, kc0, kc1,
                 qL0, qL1, oL, lsL);
    }
  }

  // l reduction: sum across the 4 quads (same l15 = same q column)
  lsH += __shfl_xor(lsH, 16); lsH += __shfl_xor(lsH, 32);
  lsL += __shfl_xor(lsL, 16); lsL += __shfl_xor(lsL, 32);
  const float rlH = fast_rcp(lsH);
  const float rlL = fast_rcp(lsL);

  // O^T: col q = l15, row d = dt*16 + quad*4 + r -> packed ushort4 per dt
#pragma unroll
  for (int dt = 0; dt < 4; dt++) {
    const int dbase = h * DH_ + dt * 16 + quad * 4;
    ushort4 pa, pb;
    pa.x = f2bf(oH[dt][0] * rlH); pa.y = f2bf(oH[dt][1] * rlH);
    pa.z = f2bf(oH[dt][2] * rlH); pa.w = f2bf(oH[dt][3] * rlH);
    pb.x = f2bf(oL[dt][0] * rlL); pb.y = f2bf(oL[dt][1] * rlL);
    pb.z = f2bf(oL[dt][2] * rlL); pb.w = f2bf(oL[dt][3] * rlL);
    *(ushort4*)(Y + (size_t)(b * T_ + qwH + l15) * D_ + dbase) = pa;
    *(ushort4*)(Y + (size_t)(b * T_ + qwL + l15) * D_ + dbase) = pb;
  }
}

// ---------------------------------------------------------------------------
// LayerNorm over D=768, fp32 in -> bf16 out. 1 block / row.
// ---------------------------------------------------------------------------
__device__ __forceinline__ void ln_row(
    const float* __restrict__ X, const float* __restrict__ g,
    const float* __restrict__ be, u16* __restrict__ out, int row)
{
  const float* x = X + (size_t)row * D_;
  const int t = threadIdx.x;
  const float v0 = x[t], v1 = x[t + 256], v2 = x[t + 512];
  float s = v0 + v1 + v2;
  float sq = v0 * v0 + v1 * v1 + v2 * v2;
#pragma unroll
  for (int off = 1; off < 64; off <<= 1) {
    s  += __shfl_xor(s, off);
    sq += __shfl_xor(sq, off);
  }
  __shared__ float ws_[4], wq_[4];
  const int wv = t >> 6, lane = t & 63;
  if (lane == 0) { ws_[wv] = s; wq_[wv] = sq; }
  __syncthreads();
  s  = ws_[0] + ws_[1] + ws_[2] + ws_[3];
  sq = wq_[0] + wq_[1] + wq_[2] + wq_[3];
  const float mean = s * (1.f / 768.f);
  const float var  = sq * (1.f / 768.f) - mean * mean;
  const float rstd = rsqrtf(var + 1e-5f);
  u16* o = out + (size_t)row * D_;
  int c = t;
  o[c] = f2bf((v0 - mean) * rstd * g[c] + be[c]); c += 256;
  o[c] = f2bf((v1 - mean) * rstd * g[c] + be[c]); c += 256;
  o[c] = f2bf((v2 - mean) * rstd * g[c] + be[c]);
}

__global__ __launch_bounds__(256) void ln_kernel(
    const float* __restrict__ X, const float* __restrict__ g,
    const float* __restrict__ be, u16* __restrict__ out)
{
  ln_row(X, g, be, out, blockIdx.x);
}

// ---------------------------------------------------------------------------
// Prep kernel: LN1 (blocks [0,8192)) + all weight converts (one launch):
//   blocks [8192, 8336)   : w_o 768x768 transpose-convert -> woT
//   blocks [8336, 33680)  : flat fp32->bf16 of w_q|w_k|w_v -> wqkv, W1, W2
// ---------------------------------------------------------------------------
__global__ __launch_bounds__(256) void prep_kernel(
    const float* __restrict__ X, const float* __restrict__ g1,
    const float* __restrict__ be1, u16* __restrict__ xln,
    const float* __restrict__ w_q, const float* __restrict__ w_k,
    const float* __restrict__ w_v, const float* __restrict__ W1,
    const float* __restrict__ W2, const float* __restrict__ w_o,
    u16* __restrict__ wqkv, u16* __restrict__ W1b,
    u16* __restrict__ W2b, u16* __restrict__ woT)
{
  if (blockIdx.x < NTOK_) {
    ln_row(X, g1, be1, xln, blockIdx.x);
    return;
  }
  const int id = blockIdx.x - NTOK_;
  if (id < 144) {
    __shared__ float tile[64][65];
    const int bx = id % 12, by = id / 12;
    const int rr0 = by * 64, cc0 = bx * 64;
    for (int idx = threadIdx.x; idx < 4096; idx += 256) {
      const int i = idx >> 6, j = idx & 63;
      tile[i][j] = w_o[(size_t)(rr0 + i) * D_ + cc0 + j];
    }
    __syncthreads();
    for (int idx = threadIdx.x; idx < 4096; idx += 256) {
      const int i = idx >> 6, j = idx & 63;
      woT[(size_t)(cc0 + i) * D_ + rr0 + j] = f2bf(tile[j][i]);
    }
  } else {
    const int WQN = H_ * DH_ * D_;            // 589824
    const int i = (id - 144) * 256 + threadIdx.x;
    if (i < 3 * WQN) {
      const float* src = (i < WQN) ? w_q : (i < 2 * WQN ? w_k : w_v);
      const int off = (i < WQN) ? i : (i < 2 * WQN ? i - WQN : i - 2 * WQN);
      wqkv[i] = f2bf(src[off]);
    } else if (i < 3 * WQN + DFF_ * D_) {
      const int off = i - 3 * WQN;
      W1b[off] = f2bf(W1[off]);
    } else {
      const int off = i - 3 * WQN - DFF_ * D_;
      W2b[off] = f2bf(W2[off]);
    }
  }
}

// ---------------------------------------------------------------------------
extern "C" void kernel_launch(void* const* d_in, const int* in_sizes, int n_in,
                              void* d_out, int out_size, void* d_ws, size_t ws_size,
                              hipStream_t stream) {
  const float* X   = (const float*)d_in[0];
  const float* w_q = (const float*)d_in[1];
  const float* w_k = (const float*)d_in[2];
  const float* w_v = (const float*)d_in[3];
  const float* w_o = (const float*)d_in[4];
  const float* W1  = (const float*)d_in[5];
  const float* b1  = (const float*)d_in[6];
  const float* W2  = (const float*)d_in[7];
  const float* b2  = (const float*)d_in[8];
  const float* g1  = (const float*)d_in[9];
  const float* be1 = (const float*)d_in[10];
  const float* g2  = (const float*)d_in[11];
  const float* be2 = (const float*)d_in[12];
  float* out = (float*)d_out;

  char* ws = (char*)d_ws;
  // region A: qkv(37.7M)+vt(12.6M) -> later aliased by h(50.3M)
  u16*   qkv  = (u16*)(ws + 0);
  u16*   vt   = (u16*)(ws + 37748736);
  u16*   hbuf = (u16*)(ws + 0);
  u16*   xln  = (u16*)(ws + 50331648);   // aliased: xln then x2ln
  u16*   Ybuf = (u16*)(ws + 62914560);
  float* X1   = (float*)(ws + 75497472);
  u16*   wqkv = (u16*)(ws + 100663296);
  u16*   woT  = (u16*)(ws + 104202240);
  u16*   W1b  = (u16*)(ws + 105381888);
  u16*   W2b  = (u16*)(ws + 110100480);  // end 114819072

  // LN1 + all weight converts in one launch
  prep_kernel<<<NTOK_ + 25488, 256, 0, stream>>>(
      X, g1, be1, xln, w_q, w_k, w_v, W1, W2, w_o, wqkv, W1b, W2b, woT);

  // QKV: [8192,768] x [2304,768]^T; Q cols pre-scaled; V routed to vt transposed
  gemm_bt<false, false, false, true, true, 128, true, false>
      <<<dim3(64, 18), 256, 0, stream>>>(
      xln, wqkv, nullptr, nullptr, qkv, vt, NTOK_, QKVN_, D_);

  attn_kernel<<<dim3(16, 12, 4), 256, 0, stream>>>(qkv, vt, Ybuf);

  // O-proj + residual X -> X1 (fp32); BN=64, counted-vmcnt pipeline
  gemm_bt<false, false, true, false, false, 64, false, true>
      <<<dim3(64, 12), 256, 0, stream>>>(
      Ybuf, woT, nullptr, X, X1, nullptr, NTOK_, D_, D_);

  ln_kernel<<<NTOK_, 256, 0, stream>>>(X1, g2, be2, xln);

  // MLP1: +b1, ReLU -> bf16 h; BN=128 (R10 config — best measured)
  gemm_bt<true, true, false, true, false, 128, false, false>
      <<<dim3(64, 24), 256, 0, stream>>>(
      xln, W1b, b1, nullptr, hbuf, nullptr, NTOK_, DFF_, D_);

  // MLP2: +b2, +X1 -> d_out (fp32); BN=64, counted-vmcnt pipeline (48 kt)
  gemm_bt<true, false, true, false, false, 64, false, true>
      <<<dim3(64, 12), 256, 0, stream>>>(
      hbuf, W2b, b2, X1, out, nullptr, NTOK_, D_, DFF_);
}